// Round 12
// baseline (136.216 us; speedup 1.0000x reference)
//
#include <hip/hip_runtime.h>
#include <hip/hip_bf16.h>

#define NPTS 4096
#define NROWS 8192
#define DIM 128
#define GEMM_BLOCKS 1024
#define HCELL 0.25f
#define LOW (-4.0f)
#define CAP 16
#define NCELLS 32768        // 32^3 per batch
#define OVCAP 4096

typedef __attribute__((ext_vector_type(8))) short bf16x8;
typedef __attribute__((ext_vector_type(4))) float f32x4;

__device__ __forceinline__ int cellcoord(float v) {
    int c = (int)floorf((v - LOW) / HCELL);
    return c < 0 ? 0 : (c > 31 ? 31 : c);
}

// ---------- K1: xW GEMM (R7-verified) + point binning ----------
__global__ __launch_bounds__(256) void k1_gemm_bin(const float* __restrict__ x,
        const float* __restrict__ pos, const float* __restrict__ W,
        __hip_bfloat16* __restrict__ xWb, unsigned* __restrict__ cellCnt,
        float4* __restrict__ cellPts, unsigned* __restrict__ ovfCnt,
        float4* __restrict__ ovfList) {
    int b = blockIdx.x;
    if (b >= GEMM_BLOCKS) {
        int t = (b - GEMM_BLOCKS) * 256 + threadIdx.x;   // 0..8191
        int batch = t >> 12;
        const float* p = pos + (size_t)t * 3;
        float px = p[0], py = p[1], pz = p[2];
        int cx = cellcoord(px), cy = cellcoord(py), cz = cellcoord(pz);
        int cid = ((batch * 32 + cz) * 32 + cy) * 32 + cx;
        unsigned slot = atomicAdd(&cellCnt[cid], 1u);
        float4 rec = make_float4(px, py, pz, __uint_as_float((unsigned)(t & (NPTS - 1))));
        if (slot < CAP) cellPts[(size_t)cid * CAP + slot] = rec;
        else { unsigned o = atomicAdd(&ovfCnt[batch], 1u);
               if (o < OVCAP) ovfList[(size_t)batch * OVCAP + o] = rec; }
        return;
    }
    int wave = threadIdx.x >> 6, lane = threadIdx.x & 63;
    int tile = b * 4 + wave;
    int m0 = (tile >> 3) << 4, n0 = (tile & 7) << 4;
    int r = lane & 15, kg = lane >> 4;
    const float* xr = x + (size_t)(m0 + r) * DIM + kg * 8;
    const float* wc = W + (size_t)(kg * 8) * DIM + (n0 + r);
    f32x4 acc = {0.f, 0.f, 0.f, 0.f};
    union { __hip_bfloat16 h; short s; } u;
#pragma unroll
    for (int kb = 0; kb < 4; ++kb) {
        float4 a0 = *(const float4*)(xr + kb * 32);
        float4 a1 = *(const float4*)(xr + kb * 32 + 4);
        bf16x8 af, bf;
        u.h = __float2bfloat16(a0.x); af[0] = u.s;
        u.h = __float2bfloat16(a0.y); af[1] = u.s;
        u.h = __float2bfloat16(a0.z); af[2] = u.s;
        u.h = __float2bfloat16(a0.w); af[3] = u.s;
        u.h = __float2bfloat16(a1.x); af[4] = u.s;
        u.h = __float2bfloat16(a1.y); af[5] = u.s;
        u.h = __float2bfloat16(a1.z); af[6] = u.s;
        u.h = __float2bfloat16(a1.w); af[7] = u.s;
#pragma unroll
        for (int i = 0; i < 8; ++i) {
            u.h = __float2bfloat16(wc[(size_t)(kb * 32 + i) * DIM]);
            bf[i] = u.s;
        }
        acc = __builtin_amdgcn_mfma_f32_16x16x32_bf16(af, bf, acc, 0, 0, 0);
    }
    int col = n0 + r, rbase = m0 + (kg << 2);
#pragma unroll
    for (int reg = 0; reg < 4; ++reg)
        xWb[(size_t)(rbase + reg) * DIM + col] = __float2bfloat16(acc[reg]);
}

// ---------- exact f64 key machinery (verified R4-R11) ----------
__device__ __forceinline__ double mkkey(float d2, int j) {
    return __longlong_as_double(__double_as_longlong((double)d2) |
                                (unsigned long long)(unsigned)j);
}
__device__ __forceinline__ void kins(double& k0, double& k1, double& k2,
                                     double& k3, double s) {
    double c = fmax(k0, s); k0 = fmin(k0, s);
    double t = fmax(k1, c); k1 = fmin(k1, c); c = t;
    t = fmax(k2, c);        k2 = fmin(k2, c); c = t;
    k3 = fmin(k3, c);
}
__device__ __forceinline__ void kmerge(double& a0, double& a1, double& a2,
                                       double& a3, double b0, double b1,
                                       double b2, double b3) {
    double m0 = fmin(a0, b3), m1 = fmin(a1, b2);
    double m2 = fmin(a2, b1), m3 = fmin(a3, b0);
    double t0 = fmin(m0, m2), t2 = fmax(m0, m2);
    double t1 = fmin(m1, m3), t3 = fmax(m1, m3);
    a0 = fmin(t0, t1); a1 = fmax(t0, t1);
    a2 = fmin(t2, t3); a3 = fmax(t2, t3);
}

// ---------- K2: grid kNN. Lane per storage slot (cell-major => coherent waves).
// Phase1: 3^3 box. Phase2: shell-2. Exact stop: unscanned cells >= dbox away.
// Fallback: wave-cooperative brute (proven R4 path). Overflow list always added.
__global__ __launch_bounds__(256) void knn(const unsigned* __restrict__ cellCnt,
        const float4* __restrict__ cellPts, const unsigned* __restrict__ ovfCnt,
        const float4* __restrict__ ovfList, const float* __restrict__ pos,
        float4* __restrict__ res) {
    int g = blockIdx.x * 256 + threadIdx.x;
    int lane = threadIdx.x & 63;
    bool active = false, resolved = false, bruted = false;
    float4 me = make_float4(0.f, 0.f, 0.f, 0.f);
    int batch;
    if (g < (1 << 20)) {
        int cid = g >> 4, slot = g & 15;
        unsigned cnt = cellCnt[cid];
        unsigned cc = cnt < CAP ? cnt : CAP;
        batch = cid >> 15;
        active = (unsigned)slot < cc;
        if (active) me = cellPts[(size_t)cid * CAP + slot];
    } else {
        int o = g - (1 << 20);
        batch = o >> 12;
        int oslot = o & 4095;
        unsigned oc = ovfCnt[batch]; oc = oc < OVCAP ? oc : OVCAP;
        active = (unsigned)oslot < oc;
        if (active) me = ovfList[(size_t)batch * OVCAP + oslot];
    }
    float qx = me.x, qy = me.y, qz = me.z;
    const double INF = __builtin_inf();
    double k0 = INF, k1 = INF, k2 = INF, k3 = INF;
    int cx = cellcoord(qx), cy = cellcoord(qy), cz = cellcoord(qz);
    const unsigned* cb = cellCnt + (size_t)batch * NCELLS;
    const float4* pb4 = cellPts + (size_t)batch * NCELLS * CAP;

    if (active) {
        // ---- phase 1: 3x3x3 box (prefetched counts) ----
        unsigned cnts[27]; int lids[27];
#pragma unroll
        for (int i = 0; i < 27; ++i) {
            int dz = i / 9 - 1, dy = (i / 3) % 3 - 1, dx = i % 3 - 1;
            int nx = cx + dx, ny = cy + dy, nz = cz + dz;
            bool ok = (unsigned)nx < 32u && (unsigned)ny < 32u && (unsigned)nz < 32u;
            int lid = (nz * 32 + ny) * 32 + nx;
            lids[i] = lid;
            cnts[i] = ok ? cb[lid] : 0u;
        }
#pragma unroll 4
        for (int i = 0; i < 27; ++i) {
            unsigned c = cnts[i] < CAP ? cnts[i] : CAP;
            const float4* cp = pb4 + (size_t)lids[i] * CAP;
            for (unsigned s = 0; s < c; ++s) {
                float4 p = cp[s];
                float ddx = qx - p.x, ddy = qy - p.y, ddz = qz - p.z;
                float d2 = fmaf(ddx, ddx, fmaf(ddy, ddy, ddz * ddz));
                kins(k0, k1, k2, k3, mkkey(d2, (int)__float_as_uint(p.w)));
            }
        }
        {   // stop check, box k=1
            float dbox = 1e30f;
            if (cx - 1 > 0)  dbox = fminf(dbox, qx - (LOW + (cx - 1) * HCELL));
            if (cx + 1 < 31) dbox = fminf(dbox, (LOW + (cx + 2) * HCELL) - qx);
            if (cy - 1 > 0)  dbox = fminf(dbox, qy - (LOW + (cy - 1) * HCELL));
            if (cy + 1 < 31) dbox = fminf(dbox, (LOW + (cy + 2) * HCELL) - qy);
            if (cz - 1 > 0)  dbox = fminf(dbox, qz - (LOW + (cz - 1) * HCELL));
            if (cz + 1 < 31) dbox = fminf(dbox, (LOW + (cz + 2) * HCELL) - qz);
            resolved = ((float)k3 < 0.999f * dbox * dbox);
        }
        if (!resolved) {
            // ---- phase 2: shell k=2, per z-slab prefetch ----
            for (int sz = -2; sz <= 2; ++sz) {
                int nz = cz + sz;
                bool zok = (unsigned)nz < 32u;
                unsigned c2[25]; int l2[25];
#pragma unroll
                for (int i = 0; i < 25; ++i) {
                    int dy = i / 5 - 2, dx = i % 5 - 2;
                    bool inner = sz >= -1 && sz <= 1 && dy >= -1 && dy <= 1 &&
                                 dx >= -1 && dx <= 1;
                    int ny = cy + dy, nx = cx + dx;
                    bool ok = zok && !inner && (unsigned)ny < 32u && (unsigned)nx < 32u;
                    int lid = (nz * 32 + ny) * 32 + nx;
                    l2[i] = lid;
                    c2[i] = ok ? cb[lid] : 0u;
                }
#pragma unroll 4
                for (int i = 0; i < 25; ++i) {
                    unsigned c = c2[i] < CAP ? c2[i] : CAP;
                    const float4* cp = pb4 + (size_t)l2[i] * CAP;
                    for (unsigned s = 0; s < c; ++s) {
                        float4 p = cp[s];
                        float ddx = qx - p.x, ddy = qy - p.y, ddz = qz - p.z;
                        float d2 = fmaf(ddx, ddx, fmaf(ddy, ddy, ddz * ddz));
                        kins(k0, k1, k2, k3, mkkey(d2, (int)__float_as_uint(p.w)));
                    }
                }
            }
            float dbox = 1e30f;
            if (cx - 2 > 0)  dbox = fminf(dbox, qx - (LOW + (cx - 2) * HCELL));
            if (cx + 2 < 31) dbox = fminf(dbox, (LOW + (cx + 3) * HCELL) - qx);
            if (cy - 2 > 0)  dbox = fminf(dbox, qy - (LOW + (cy - 2) * HCELL));
            if (cy + 2 < 31) dbox = fminf(dbox, (LOW + (cy + 3) * HCELL) - qy);
            if (cz - 2 > 0)  dbox = fminf(dbox, qz - (LOW + (cz - 2) * HCELL));
            if (cz + 2 < 31) dbox = fminf(dbox, (LOW + (cz + 3) * HCELL) - qz);
            resolved = ((float)k3 < 0.999f * dbox * dbox);
        }
    }

    // ---- cooperative brute fallback (complete rescan; exact) ----
    unsigned long long mask = __ballot(active && !resolved);
    while (mask) {
        int src = __ffsll((unsigned long long)mask) - 1;
        mask &= mask - 1;
        float bx = __shfl(qx, src), by = __shfl(qy, src), bz = __shfl(qz, src);
        double c0 = INF, c1 = INF, c2 = INF, c3 = INF;
        const float* pp = pos + (size_t)batch * NPTS * 3;   // batch wave-uniform
        for (int t = 0; t < 64; ++t) {
            int j = t * 64 + lane;
            float px = pp[3 * j], py = pp[3 * j + 1], pz = pp[3 * j + 2];
            float ddx = bx - px, ddy = by - py, ddz = bz - pz;
            float d2 = fmaf(ddx, ddx, fmaf(ddy, ddy, ddz * ddz));
            kins(c0, c1, c2, c3, mkkey(d2, j));
        }
#pragma unroll
        for (int off = 1; off < 64; off <<= 1) {
            double p0 = __shfl_xor(c0, off), p1 = __shfl_xor(c1, off);
            double p2 = __shfl_xor(c2, off), p3 = __shfl_xor(c3, off);
            kmerge(c0, c1, c2, c3, p0, p1, p2, p3);
        }
        if (lane == src) { k0 = c0; k1 = c1; k2 = c2; k3 = c3; bruted = true; }
    }

    // ---- overflow candidates (cell path only; brute already complete) ----
    if (active && !bruted) {
        unsigned oc = ovfCnt[batch]; oc = oc < OVCAP ? oc : OVCAP;
        const float4* ol = ovfList + (size_t)batch * OVCAP;
        for (unsigned o = 0; o < oc; ++o) {
            float4 p = ol[o];
            float ddx = qx - p.x, ddy = qy - p.y, ddz = qz - p.z;
            float d2 = fmaf(ddx, ddx, fmaf(ddy, ddy, ddz * ddz));
            kins(k0, k1, k2, k3, mkkey(d2, (int)__float_as_uint(p.w)));
        }
    }

    if (active) {
        unsigned i0 = (unsigned)__double_as_longlong(k0) & 0xFFFu;
        unsigned i1 = (unsigned)__double_as_longlong(k1) & 0xFFFu;
        unsigned i2 = (unsigned)__double_as_longlong(k2) & 0xFFFu;
        unsigned i3 = (unsigned)__double_as_longlong(k3) & 0xFFFu;
        float d0 = (float)k0, d1 = (float)k1, d2 = (float)k2, d3 = (float)k3;
        float w0 = __expf(-(d0 + 1e-8f) * 0.5f);
        float w1 = __expf(-(d1 + 1e-8f) * 0.5f);
        float w2 = __expf(-(d2 + 1e-8f) * 0.5f);
        float w3 = __expf(-(d3 + 1e-8f) * 0.5f);
        float inv = 1.0f / (w0 + w1 + w2 + w3 + 1e-8f);
        int row = batch * NPTS + (int)__float_as_uint(me.w);
        res[2 * row] = make_float4(__uint_as_float(i0), __uint_as_float(i1),
                                   __uint_as_float(i2), __uint_as_float(i3));
        res[2 * row + 1] = make_float4(w0 * inv, w1 * inv, w2 * inv, w3 * inv);
    }
}

// ---------- K3: gather epilogue (proven R10 shape, reads res) ----------
__global__ __launch_bounds__(256) void agg_out(const float4* __restrict__ res,
        const __hip_bfloat16* __restrict__ xWb, const float* __restrict__ bias,
        float* __restrict__ out) {
    int lane = threadIdx.x & 63, wave = threadIdx.x >> 6;
    int rowbase = blockIdx.x * 8 + wave * 2;
    int batch = rowbase >> 12;
    int c = lane << 1;
    float2 bb = *(const float2*)(bias + c);
    const unsigned short* xu = (const unsigned short*)xWb;
    size_t bbase = ((size_t)batch * NPTS) << 7;
#pragma unroll
    for (int k = 0; k < 2; ++k) {
        int row = rowbase + k;
        float4 ri = res[2 * row], rw = res[2 * row + 1];
        unsigned i0 = __float_as_uint(ri.x), i1 = __float_as_uint(ri.y);
        unsigned i2 = __float_as_uint(ri.z), i3 = __float_as_uint(ri.w);
        ushort2 g0 = *(const ushort2*)(xu + bbase + ((size_t)i0 << 7) + c);
        ushort2 g1 = *(const ushort2*)(xu + bbase + ((size_t)i1 << 7) + c);
        ushort2 g2 = *(const ushort2*)(xu + bbase + ((size_t)i2 << 7) + c);
        ushort2 g3 = *(const ushort2*)(xu + bbase + ((size_t)i3 << 7) + c);
        float ox = bb.x + rw.x * __uint_as_float((unsigned)g0.x << 16)
                        + rw.y * __uint_as_float((unsigned)g1.x << 16)
                        + rw.z * __uint_as_float((unsigned)g2.x << 16)
                        + rw.w * __uint_as_float((unsigned)g3.x << 16);
        float oy = bb.y + rw.x * __uint_as_float((unsigned)g0.y << 16)
                        + rw.y * __uint_as_float((unsigned)g1.y << 16)
                        + rw.z * __uint_as_float((unsigned)g2.y << 16)
                        + rw.w * __uint_as_float((unsigned)g3.y << 16);
        *(float2*)(out + ((size_t)row << 7) + c) = make_float2(ox, oy);
    }
}

extern "C" void kernel_launch(void* const* d_in, const int* in_sizes, int n_in,
                              void* d_out, int out_size, void* d_ws, size_t ws_size,
                              hipStream_t stream) {
    const float* x    = (const float*)d_in[0];
    const float* pos  = (const float*)d_in[1];
    const float* W    = (const float*)d_in[2];
    const float* bias = (const float*)d_in[3];
    float* out = (float*)d_out;

    char* ws = (char*)d_ws;
    __hip_bfloat16* xWb = (__hip_bfloat16*)ws;                    // 2 MB
    float4* res        = (float4*)(ws + 2097152);                 // 256 KB
    unsigned* cellCnt  = (unsigned*)(ws + 2359296);               // 256 KB
    unsigned* ovfCnt   = (unsigned*)(ws + 2621440);               // 16 B
    float4* cellPts    = (float4*)(ws + 2621456);                 // 16 MB
    float4* ovfList    = (float4*)(ws + 2621456 + 16777216);      // 128 KB

    hipMemsetAsync(ws + 2359296, 0, 262160, stream);              // cnt + ovfCnt
    k1_gemm_bin<<<GEMM_BLOCKS + NROWS / 256, 256, 0, stream>>>(
        x, pos, W, xWb, cellCnt, cellPts, ovfCnt, ovfList);
    knn<<<(1 << 20) / 256 + 2 * OVCAP / 256, 256, 0, stream>>>(
        cellCnt, cellPts, ovfCnt, ovfList, pos, res);
    agg_out<<<NROWS / 8, 256, 0, stream>>>(res, xWb, bias, out);
}

// Round 13
// 84.935 us; speedup vs baseline: 1.6038x; 1.6038x over previous
//
#include <hip/hip_runtime.h>
#include <hip/hip_bf16.h>

#define NPTS 4096
#define NROWS 8192
#define DIM 128
#define GEMM_BLOCKS 1024
#define HCELL 0.25f
#define LOW (-4.0f)
#define CAP 16
#define NCELLS 32768        // 32^3 per batch
#define OVCAP 4096

typedef __attribute__((ext_vector_type(8))) short bf16x8;
typedef __attribute__((ext_vector_type(4))) float f32x4;

__device__ __forceinline__ int cellcoord(float v) {
    int c = (int)floorf((v - LOW) / HCELL);
    return c < 0 ? 0 : (c > 31 ? 31 : c);
}

// ---------- K1: xW GEMM (R7-verified) + point binning (R12-verified) ----------
__global__ __launch_bounds__(256) void k1_gemm_bin(const float* __restrict__ x,
        const float* __restrict__ pos, const float* __restrict__ W,
        __hip_bfloat16* __restrict__ xWb, unsigned* __restrict__ cellCnt,
        float4* __restrict__ cellPts, unsigned* __restrict__ ovfCnt,
        float4* __restrict__ ovfList) {
    int b = blockIdx.x;
    if (b >= GEMM_BLOCKS) {
        int t = (b - GEMM_BLOCKS) * 256 + threadIdx.x;   // 0..8191
        int batch = t >> 12;
        const float* p = pos + (size_t)t * 3;
        float px = p[0], py = p[1], pz = p[2];
        int cx = cellcoord(px), cy = cellcoord(py), cz = cellcoord(pz);
        int cid = ((batch * 32 + cz) * 32 + cy) * 32 + cx;
        unsigned slot = atomicAdd(&cellCnt[cid], 1u);
        float4 rec = make_float4(px, py, pz, __uint_as_float((unsigned)(t & (NPTS - 1))));
        if (slot < CAP) cellPts[(size_t)cid * CAP + slot] = rec;
        else { unsigned o = atomicAdd(&ovfCnt[batch], 1u);
               if (o < OVCAP) ovfList[(size_t)batch * OVCAP + o] = rec; }
        return;
    }
    int wave = threadIdx.x >> 6, lane = threadIdx.x & 63;
    int tile = b * 4 + wave;
    int m0 = (tile >> 3) << 4, n0 = (tile & 7) << 4;
    int r = lane & 15, kg = lane >> 4;
    const float* xr = x + (size_t)(m0 + r) * DIM + kg * 8;
    const float* wc = W + (size_t)(kg * 8) * DIM + (n0 + r);
    f32x4 acc = {0.f, 0.f, 0.f, 0.f};
    union { __hip_bfloat16 h; short s; } u;
#pragma unroll
    for (int kb = 0; kb < 4; ++kb) {
        float4 a0 = *(const float4*)(xr + kb * 32);
        float4 a1 = *(const float4*)(xr + kb * 32 + 4);
        bf16x8 af, bf;
        u.h = __float2bfloat16(a0.x); af[0] = u.s;
        u.h = __float2bfloat16(a0.y); af[1] = u.s;
        u.h = __float2bfloat16(a0.z); af[2] = u.s;
        u.h = __float2bfloat16(a0.w); af[3] = u.s;
        u.h = __float2bfloat16(a1.x); af[4] = u.s;
        u.h = __float2bfloat16(a1.y); af[5] = u.s;
        u.h = __float2bfloat16(a1.z); af[6] = u.s;
        u.h = __float2bfloat16(a1.w); af[7] = u.s;
#pragma unroll
        for (int i = 0; i < 8; ++i) {
            u.h = __float2bfloat16(wc[(size_t)(kb * 32 + i) * DIM]);
            bf[i] = u.s;
        }
        acc = __builtin_amdgcn_mfma_f32_16x16x32_bf16(af, bf, acc, 0, 0, 0);
    }
    int col = n0 + r, rbase = m0 + (kg << 2);
#pragma unroll
    for (int reg = 0; reg < 4; ++reg)
        xWb[(size_t)(rbase + reg) * DIM + col] = __float2bfloat16(acc[reg]);
}

// ---------- exact f64 key machinery (verified R4-R12) ----------
__device__ __forceinline__ double mkkey(float d2, int j) {
    return __longlong_as_double(__double_as_longlong((double)d2) |
                                (unsigned long long)(unsigned)j);
}
__device__ __forceinline__ void kins(double& k0, double& k1, double& k2,
                                     double& k3, double s) {
    double c = fmax(k0, s); k0 = fmin(k0, s);
    double t = fmax(k1, c); k1 = fmin(k1, c); c = t;
    t = fmax(k2, c);        k2 = fmin(k2, c); c = t;
    k3 = fmin(k3, c);
}
__device__ __forceinline__ void kmerge(double& a0, double& a1, double& a2,
                                       double& a3, double b0, double b1,
                                       double b2, double b3) {
    double m0 = fmin(a0, b3), m1 = fmin(a1, b2);
    double m2 = fmin(a2, b1), m3 = fmin(a3, b0);
    double t0 = fmin(m0, m2), t2 = fmax(m0, m2);
    double t1 = fmin(m1, m3), t3 = fmax(m1, m3);
    a0 = fmin(t0, t1); a1 = fmax(t0, t1);
    a2 = fmin(t2, t3); a3 = fmax(t2, t3);
}

// ---------- K2: wave-per-query grid kNN + fused epilogue ----------
// One wave = one query row. Lane m and m+64 own cells of the 5^3 box
// (125 cells, ~16 pts total -> parallel across lanes). Butterfly -> top4.
// Wave-uniform exact stop check (R12-verified); unresolved -> in-wave
// R4-proven brute scan. All lanes end with the keys -> epilogue in-kernel.
__global__ __launch_bounds__(256) void knn_agg(const unsigned* __restrict__ cellCnt,
        const float4* __restrict__ cellPts, const unsigned* __restrict__ ovfCnt,
        const float4* __restrict__ ovfList, const float* __restrict__ pos,
        const __hip_bfloat16* __restrict__ xWb, const float* __restrict__ bias,
        float* __restrict__ out) {
    int lane = threadIdx.x & 63;
    int wave = threadIdx.x >> 6;
    int row = blockIdx.x * 4 + wave;           // 0..8191
    int batch = row >> 12;
    int qi = row & (NPTS - 1);
    const float* pb = pos + (size_t)batch * NPTS * 3;
    float qx = pb[3 * qi], qy = pb[3 * qi + 1], qz = pb[3 * qi + 2];
    int cx = cellcoord(qx), cy = cellcoord(qy), cz = cellcoord(qz);
    const unsigned* cb = cellCnt + (size_t)batch * NCELLS;
    const float4* pb4 = cellPts + (size_t)batch * NCELLS * CAP;

    const double INF = __builtin_inf();
    double k0 = INF, k1 = INF, k2 = INF, k3 = INF;

    // ---- scan 5^3 box: lane handles cells m=lane and m=lane+64 ----
#pragma unroll
    for (int mm = 0; mm < 2; ++mm) {
        int m = lane + mm * 64;
        if (m < 125) {
            int dz = m / 25 - 2, dy = (m / 5) % 5 - 2, dx = m % 5 - 2;
            int nx = cx + dx, ny = cy + dy, nz = cz + dz;
            if ((unsigned)nx < 32u && (unsigned)ny < 32u && (unsigned)nz < 32u) {
                int lid = (nz * 32 + ny) * 32 + nx;
                unsigned c = cb[lid]; c = c < CAP ? c : CAP;
                const float4* cp = pb4 + (size_t)lid * CAP;
                for (unsigned s = 0; s < c; ++s) {
                    float4 p = cp[s];
                    float ddx = qx - p.x, ddy = qy - p.y, ddz = qz - p.z;
                    float d2 = fmaf(ddx, ddx, fmaf(ddy, ddy, ddz * ddz));
                    kins(k0, k1, k2, k3, mkkey(d2, (int)__float_as_uint(p.w)));
                }
            }
        }
    }
    // butterfly -> every lane holds box top-4
#pragma unroll
    for (int off = 1; off < 64; off <<= 1) {
        double p0 = __shfl_xor(k0, off), p1 = __shfl_xor(k1, off);
        double p2 = __shfl_xor(k2, off), p3 = __shfl_xor(k3, off);
        kmerge(k0, k1, k2, k3, p0, p1, p2, p3);
    }

    // ---- exact stop check (wave-uniform; R12-verified criterion) ----
    float dbox = 1e30f;
    if (cx - 2 > 0)  dbox = fminf(dbox, qx - (LOW + (cx - 2) * HCELL));
    if (cx + 2 < 31) dbox = fminf(dbox, (LOW + (cx + 3) * HCELL) - qx);
    if (cy - 2 > 0)  dbox = fminf(dbox, qy - (LOW + (cy - 2) * HCELL));
    if (cy + 2 < 31) dbox = fminf(dbox, (LOW + (cy + 3) * HCELL) - qy);
    if (cz - 2 > 0)  dbox = fminf(dbox, qz - (LOW + (cz - 2) * HCELL));
    if (cz + 2 < 31) dbox = fminf(dbox, (LOW + (cz + 3) * HCELL) - qz);
    bool resolved = ((float)k3 < 0.999f * dbox * dbox) && ((float)k3 < 1e29f);

    if (!resolved) {
        // ---- in-wave brute scan (R4-proven, complete & exact) ----
        k0 = INF; k1 = INF; k2 = INF; k3 = INF;
#pragma unroll 4
        for (int t = 0; t < NPTS / 64; ++t) {
            int j = t * 64 + lane;
            float px = pb[3 * j], py = pb[3 * j + 1], pz = pb[3 * j + 2];
            float ddx = qx - px, ddy = qy - py, ddz = qz - pz;
            float d2 = fmaf(ddx, ddx, fmaf(ddy, ddy, ddz * ddz));
            kins(k0, k1, k2, k3, mkkey(d2, j));
        }
#pragma unroll
        for (int off = 1; off < 64; off <<= 1) {
            double p0 = __shfl_xor(k0, off), p1 = __shfl_xor(k1, off);
            double p2 = __shfl_xor(k2, off), p3 = __shfl_xor(k3, off);
            kmerge(k0, k1, k2, k3, p0, p1, p2, p3);
        }
    } else {
        // ---- overflow candidates (expected 0; uniform across lanes) ----
        unsigned oc = ovfCnt[batch]; oc = oc < OVCAP ? oc : OVCAP;
        const float4* ol = ovfList + (size_t)batch * OVCAP;
        for (unsigned o = 0; o < oc; ++o) {
            float4 p = ol[o];
            float ddx = qx - p.x, ddy = qy - p.y, ddz = qz - p.z;
            float d2 = fmaf(ddx, ddx, fmaf(ddy, ddy, ddz * ddz));
            kins(k0, k1, k2, k3, mkkey(d2, (int)__float_as_uint(p.w)));
        }
    }

    // ---- fused epilogue: lane owns channels (2*lane, 2*lane+1) ----
    unsigned i0 = (unsigned)__double_as_longlong(k0) & 0xFFFu;
    unsigned i1 = (unsigned)__double_as_longlong(k1) & 0xFFFu;
    unsigned i2 = (unsigned)__double_as_longlong(k2) & 0xFFFu;
    unsigned i3 = (unsigned)__double_as_longlong(k3) & 0xFFFu;
    float d0 = (float)k0, d1 = (float)k1, d2 = (float)k2, d3 = (float)k3;
    float w0 = __expf(-(d0 + 1e-8f) * 0.5f);
    float w1 = __expf(-(d1 + 1e-8f) * 0.5f);
    float w2 = __expf(-(d2 + 1e-8f) * 0.5f);
    float w3 = __expf(-(d3 + 1e-8f) * 0.5f);
    float inv = 1.0f / (w0 + w1 + w2 + w3 + 1e-8f);
    w0 *= inv; w1 *= inv; w2 *= inv; w3 *= inv;
    int c = lane << 1;
    float2 bb = *(const float2*)(bias + c);
    const unsigned short* xu = (const unsigned short*)xWb;
    size_t bbase = ((size_t)batch * NPTS) << 7;
    ushort2 g0 = *(const ushort2*)(xu + bbase + ((size_t)i0 << 7) + c);
    ushort2 g1 = *(const ushort2*)(xu + bbase + ((size_t)i1 << 7) + c);
    ushort2 g2 = *(const ushort2*)(xu + bbase + ((size_t)i2 << 7) + c);
    ushort2 g3 = *(const ushort2*)(xu + bbase + ((size_t)i3 << 7) + c);
    float ox = bb.x + w0 * __uint_as_float((unsigned)g0.x << 16)
                    + w1 * __uint_as_float((unsigned)g1.x << 16)
                    + w2 * __uint_as_float((unsigned)g2.x << 16)
                    + w3 * __uint_as_float((unsigned)g3.x << 16);
    float oy = bb.y + w0 * __uint_as_float((unsigned)g0.y << 16)
                    + w1 * __uint_as_float((unsigned)g1.y << 16)
                    + w2 * __uint_as_float((unsigned)g2.y << 16)
                    + w3 * __uint_as_float((unsigned)g3.y << 16);
    *(float2*)(out + ((size_t)row << 7) + c) = make_float2(ox, oy);
}

extern "C" void kernel_launch(void* const* d_in, const int* in_sizes, int n_in,
                              void* d_out, int out_size, void* d_ws, size_t ws_size,
                              hipStream_t stream) {
    const float* x    = (const float*)d_in[0];
    const float* pos  = (const float*)d_in[1];
    const float* W    = (const float*)d_in[2];
    const float* bias = (const float*)d_in[3];
    float* out = (float*)d_out;

    char* ws = (char*)d_ws;
    __hip_bfloat16* xWb = (__hip_bfloat16*)ws;                    // 2 MB
    unsigned* cellCnt  = (unsigned*)(ws + 2097152);               // 256 KB
    unsigned* ovfCnt   = (unsigned*)(ws + 2359296);               // 16 B
    float4* cellPts    = (float4*)(ws + 2359312);                 // 16 MB
    float4* ovfList    = (float4*)(ws + 2359312 + 16777216);      // 128 KB

    hipMemsetAsync(ws + 2097152, 0, 262160, stream);              // cellCnt + ovfCnt
    k1_gemm_bin<<<GEMM_BLOCKS + NROWS / 256, 256, 0, stream>>>(
        x, pos, W, xWb, cellCnt, cellPts, ovfCnt, ovfList);
    knn_agg<<<NROWS / 4, 256, 0, stream>>>(
        cellCnt, cellPts, ovfCnt, ovfList, pos, xWb, bias, out);
}